// Round 16
// baseline (202.674 us; speedup 1.0000x reference)
//
#include <hip/hip_runtime.h>
#include <math.h>
#include <stdint.h>

#define NN 1024
#define ROWS 4096
#define NBL 4

typedef _Float16 h8 __attribute__((ext_vector_type(8)));
typedef _Float16 h4 __attribute__((ext_vector_type(4)));
typedef float f4 __attribute__((ext_vector_type(4)));

__device__ __forceinline__ float fast_silu(float x) {
    float e = __builtin_amdgcn_exp2f(-1.4426950408889634f * x);
    return x * __builtin_amdgcn_rcpf(1.0f + e);
}

// async global->LDS, 16B/lane; LDS dest = wave-uniform base + lane*16
__device__ __forceinline__ void gl16(const void* gp, void* lp) {
    __builtin_amdgcn_global_load_lds(
        (const __attribute__((address_space(1))) uint32_t*)gp,
        (__attribute__((address_space(3))) uint32_t*)lp, 16, 0, 0);
}

__device__ __forceinline__ float wred(float s) {
    #pragma unroll
    for (int off = 1; off < 64; off <<= 1) s += __shfl_xor(s, off);
    return s;
}

// ---------------------------------------------------------------- prep: weight transposes + init+ln1(l=0)
__global__ __launch_bounds__(256) void k_prep(const float* __restrict__ wuvqk,
                                              _Float16* __restrict__ wuT,
                                              const float* __restrict__ wo,
                                              _Float16* __restrict__ woT,
                                              const float* __restrict__ seq,
                                              const float* __restrict__ pos,
                                              const int* __restrict__ slen,
                                              const float* __restrict__ g,
                                              const float* __restrict__ bt,
                                              _Float16* __restrict__ O,
                                              float* __restrict__ Xw) {
    __shared__ _Float16 T[64][66];
    int u = blockIdx.x, tid = threadIdx.x;
    if (u < 1280) {
        const float* s; _Float16* d; int N, n0, k0;
        if (u < 1024) {
            int z = u >> 8, t = u & 255;
            N = 2048; s = wuvqk + (size_t)z * 512 * 2048; d = wuT + (size_t)z * 2048 * 512;
            n0 = (t & 31) << 6; k0 = (t >> 5) << 6;
        } else {
            int v = u - 1024; int z = v >> 6, t = v & 63;
            N = 512; s = wo + (size_t)z * 512 * 512; d = woT + (size_t)z * 512 * 512;
            n0 = (t & 7) << 6; k0 = (t >> 3) << 6;
        }
        int tx = tid & 63, ty = tid >> 6;
        #pragma unroll
        for (int q = 0; q < 16; ++q)
            T[(q << 2) + ty][tx] = (_Float16)s[(size_t)(k0 + (q << 2) + ty) * N + n0 + tx];
        __syncthreads();
        #pragma unroll
        for (int q = 0; q < 16; ++q)
            d[(size_t)(n0 + (q << 2) + ty) * 512 + k0 + tx] = T[tx][(q << 2) + ty];
    } else {
        int vb = u - 1280;
        int w = tid >> 6, lane = tid & 63;
        int c = lane << 3;
        #pragma unroll
        for (int rr = 0; rr < 2; ++rr) {
            int row = (vb << 3) + (w << 1) + rr;
            int b = row >> 10, n = row & (NN - 1);
            float m = (n < slen[b]) ? 1.0f : 0.0f;
            const float4* sp = (const float4*)&seq[(size_t)row * 512 + c];
            const float4* pp = (const float4*)&pos[(size_t)n * 512 + c];
            const float SD = 22.627416997969522f;
            float4 s0 = sp[0], s1 = sp[1], p0 = pp[0], p1 = pp[1];
            float v[8];
            v[0]=(s0.x*SD+p0.x)*m; v[1]=(s0.y*SD+p0.y)*m; v[2]=(s0.z*SD+p0.z)*m; v[3]=(s0.w*SD+p0.w)*m;
            v[4]=(s1.x*SD+p1.x)*m; v[5]=(s1.y*SD+p1.y)*m; v[6]=(s1.z*SD+p1.z)*m; v[7]=(s1.w*SD+p1.w)*m;
            float4 o0, o1;
            o0.x=v[0]; o0.y=v[1]; o0.z=v[2]; o0.w=v[3];
            o1.x=v[4]; o1.y=v[5]; o1.z=v[6]; o1.w=v[7];
            float4* xp = (float4*)&Xw[(size_t)row * 512 + c];
            xp[0] = o0; xp[1] = o1;

            float s = v[0]+v[1]+v[2]+v[3]+v[4]+v[5]+v[6]+v[7];
            s = wred(s);
            float mu = s * (1.0f / 512.0f);
            float ss = 0.0f;
            #pragma unroll
            for (int i = 0; i < 8; ++i) { float d = v[i] - mu; ss += d * d; }
            ss = wred(ss);
            float rs = rsqrtf(ss * (1.0f / 512.0f) + 1e-6f);

            const float4* gp = (const float4*)&g[c];
            const float4* bp = (const float4*)&bt[c];
            float4 g0 = gp[0], g1 = gp[1], b0 = bp[0], b1 = bp[1];
            float gg[8] = {g0.x,g0.y,g0.z,g0.w,g1.x,g1.y,g1.z,g1.w};
            float bb[8] = {b0.x,b0.y,b0.z,b0.w,b1.x,b1.y,b1.z,b1.w};
            h8 oh;
            #pragma unroll
            for (int i = 0; i < 8; ++i) oh[i] = (_Float16)((v[i] - mu) * rs * gg[i] + bb[i]);
            *(h8*)&O[(size_t)row * 512 + c] = oh;
        }
    }
}

// ---------------------------------------------------------------- wave-level layernorm -> fp16
template<int MODE>
__global__ __launch_bounds__(256) void k_lnw(const float* __restrict__ X,
                                             const float* __restrict__ X2,
                                             const float* __restrict__ X3,
                                             const float* __restrict__ g,
                                             const float* __restrict__ bt,
                                             _Float16* __restrict__ O,
                                             const _Float16* __restrict__ U) {
    int tid = threadIdx.x;
    int w = tid >> 6, lane = tid & 63;
    int c = lane << 3;
    #pragma unroll
    for (int rr = 0; rr < 2; ++rr) {
        int row = (blockIdx.x << 3) + (w << 1) + rr;
        const float4* xp = (const float4*)&X[(size_t)row * 512 + c];
        float4 a = xp[0], b4 = xp[1];
        float v[8] = {a.x, a.y, a.z, a.w, b4.x, b4.y, b4.z, b4.w};
        if (MODE == 2) {
            int nn = row & (NN - 1);
            if (nn >= 384) {
                const float4* qp = (const float4*)&X2[(size_t)row * 512 + c];
                float4 t0 = qp[0], t1 = qp[1];
                v[0]+=t0.x; v[1]+=t0.y; v[2]+=t0.z; v[3]+=t0.w;
                v[4]+=t1.x; v[5]+=t1.y; v[6]+=t1.z; v[7]+=t1.w;
            }
            if (nn >= 768) {
                const float4* qp = (const float4*)&X3[(size_t)row * 512 + c];
                float4 t0 = qp[0], t1 = qp[1];
                v[0]+=t0.x; v[1]+=t0.y; v[2]+=t0.z; v[3]+=t0.w;
                v[4]+=t1.x; v[5]+=t1.y; v[6]+=t1.z; v[7]+=t1.w;
            }
        }
        float s = v[0]+v[1]+v[2]+v[3]+v[4]+v[5]+v[6]+v[7];
        s = wred(s);
        float mu = s * (1.0f / 512.0f);
        float ss = 0.0f;
        #pragma unroll
        for (int i = 0; i < 8; ++i) { float d = v[i] - mu; ss += d * d; }
        ss = wred(ss);
        float rs = rsqrtf(ss * (1.0f / 512.0f) + 1e-6f);

        const float4* gp = (const float4*)&g[c];
        const float4* bp = (const float4*)&bt[c];
        float4 g0 = gp[0], g1 = gp[1], b0 = bp[0], b1 = bp[1];
        float gg[8] = {g0.x,g0.y,g0.z,g0.w,g1.x,g1.y,g1.z,g1.w};
        float bb[8] = {b0.x,b0.y,b0.z,b0.w,b1.x,b1.y,b1.z,b1.w};
        float o[8];
        #pragma unroll
        for (int i = 0; i < 8; ++i) o[i] = (v[i] - mu) * rs * gg[i] + bb[i];
        if (MODE == 2) {
            h8 uu = *(const h8*)&U[(size_t)row * 2048 + c];
            #pragma unroll
            for (int i = 0; i < 8; ++i) o[i] *= (float)uu[i];
        }
        h8 oh;
        #pragma unroll
        for (int i = 0; i < 8; ++i) oh[i] = (_Float16)o[i];
        *(h8*)&O[(size_t)row * 512 + c] = oh;
    }
}

// ---------------------------------------------------------------- final L2 norm (wave/row)
__global__ __launch_bounds__(256) void k_normw(float* __restrict__ X) {
    int tid = threadIdx.x;
    int w = tid >> 6, lane = tid & 63;
    int c = lane << 3;
    #pragma unroll
    for (int rr = 0; rr < 2; ++rr) {
        int row = (blockIdx.x << 3) + (w << 1) + rr;
        float4* xp = (float4*)&X[(size_t)row * 512 + c];
        float4 a = xp[0], b4 = xp[1];
        float ss = a.x*a.x + a.y*a.y + a.z*a.z + a.w*a.w +
                   b4.x*b4.x + b4.y*b4.y + b4.z*b4.z + b4.w*b4.w;
        ss = wred(ss);
        float sc = 1.0f / fmaxf(sqrtf(ss), 1e-6f);
        a.x*=sc; a.y*=sc; a.z*=sc; a.w*=sc; b4.x*=sc; b4.y*=sc; b4.z*=sc; b4.w*=sc;
        xp[0] = a; xp[1] = b4;
    }
}

// ---------------------------------------------------------------- MFMA GEMM (fp16 in, f32 acc)
template<int EPI, int BM, int BN, int WAVES, int WGR, int WGC>
__global__ __launch_bounds__(WAVES * 64) void k_gemm(const _Float16* __restrict__ A,
                                                     const _Float16* __restrict__ Bm,
                                                     _Float16* __restrict__ Cu,
                                                     _Float16* __restrict__ vT,
                                                     const float* __restrict__ bo,
                                                     const int* __restrict__ slen,
                                                     float* __restrict__ Xio) {
    constexpr int WR = BM / WGR / 16;
    constexpr int WC = BN / WGC / 16;
    constexpr int QA = BM * 8 / (WAVES * 64);
    constexpr int QB = BN * 8 / (WAVES * 64);
    __shared__ _Float16 smem[2 * 64 * (BM + BN)];
    _Float16* AsB = smem;                    // [2][BM*64]
    _Float16* BsB = smem + 2 * BM * 64;      // [2][BN*64]
    int tid = threadIdx.x;
    int w = tid >> 6, lane = tid & 63;
    int t = lane & 15, gq = lane >> 4;
    int flat = blockIdx.y * gridDim.x + blockIdx.x;
    int cpx = (gridDim.x * gridDim.y) >> 3;
    int f2 = (flat & 7) * cpx + (flat >> 3);
    int bx = f2 % gridDim.x, by = f2 / gridDim.x;
    int row0 = by * BM, col0 = bx * BN;
    int wr = (w / WGC) * (BM / WGR), wc = (w % WGC) * (BN / WGC);

    f4 zero4 = {0.0f, 0.0f, 0.0f, 0.0f};
    f4 acc[WR][WC];
    #pragma unroll
    for (int i = 0; i < WR; ++i)
        #pragma unroll
        for (int j = 0; j < WC; ++j) acc[i][j] = zero4;

    auto stage = [&](int buf, int k0) {
        _Float16* As = AsB + buf * BM * 64;
        _Float16* Bs = BsB + buf * BN * 64;
        #pragma unroll
        for (int q = 0; q < QA; ++q) {
            int s = (q * WAVES + w) * 64 + lane;
            int r = s >> 3, cs = (s & 7) ^ (r & 7);
            gl16(A + (size_t)(row0 + r) * 512 + k0 + (cs << 3),
                 (char*)As + (size_t)(q * WAVES + w) * 1024);
        }
        #pragma unroll
        for (int q = 0; q < QB; ++q) {
            int s = (q * WAVES + w) * 64 + lane;
            int r = s >> 3, cs = (s & 7) ^ (r & 7);
            gl16(Bm + (size_t)(col0 + r) * 512 + k0 + (cs << 3),
                 (char*)Bs + (size_t)(q * WAVES + w) * 1024);
        }
    };

    stage(0, 0);
    int cur = 0;
    for (int k0 = 0; k0 < 512; k0 += 64) {
        __syncthreads();
        if (k0 + 64 < 512) stage(cur ^ 1, k0 + 64);
        const char* As = (const char*)(AsB + cur * BM * 64);
        const char* Bs = (const char*)(BsB + cur * BN * 64);
        h8 af[WR][2], bf[WC][2];
        #pragma unroll
        for (int i = 0; i < WR; ++i) {
            int rl = wr + (i << 4) + t;
            #pragma unroll
            for (int ks = 0; ks < 2; ++ks)
                af[i][ks] = *(const h8*)(As + rl * 128 + (((gq + (ks << 2)) ^ (rl & 7)) << 4));
        }
        #pragma unroll
        for (int j = 0; j < WC; ++j) {
            int nl = wc + (j << 4) + t;
            #pragma unroll
            for (int ks = 0; ks < 2; ++ks)
                bf[j][ks] = *(const h8*)(Bs + nl * 128 + (((gq + (ks << 2)) ^ (nl & 7)) << 4));
        }
        #pragma unroll
        for (int i = 0; i < WR; ++i)
            #pragma unroll
            for (int j = 0; j < WC; ++j) {
                acc[i][j] = __builtin_amdgcn_mfma_f32_16x16x32_f16(af[i][0], bf[j][0], acc[i][j], 0, 0, 0);
                acc[i][j] = __builtin_amdgcn_mfma_f32_16x16x32_f16(af[i][1], bf[j][1], acc[i][j], 0, 0, 0);
            }
        cur ^= 1;
    }

    if (EPI == 0) {
        _Float16* E = smem;   // 128*136 h2 = 34816 B
        bool vblk = (col0 >= 512 && col0 < 1024);
        __syncthreads();
        if (vblk) {
            #pragma unroll
            for (int i = 0; i < WR; ++i)
                #pragma unroll
                for (int j = 0; j < WC; ++j) {
                    int cl = wc + (j << 4) + t;
                    int rl = wr + (i << 4) + (gq << 2);
                    h4 pk;
                    #pragma unroll
                    for (int rr = 0; rr < 4; ++rr) pk[rr] = (_Float16)fast_silu(acc[i][j][rr]);
                    *(h4*)&E[cl * 136 + rl] = pk;   // E_T[d][n]
                }
        } else {
            #pragma unroll
            for (int i = 0; i < WR; ++i)
                #pragma unroll
                for (int j = 0; j < WC; ++j) {
                    int cl = wc + (j << 4) + t;
                    int rl = wr + (i << 4) + (gq << 2);
                    #pragma unroll
                    for (int rr = 0; rr < 4; ++rr)
                        E[(rl + rr) * 136 + cl] = (_Float16)fast_silu(acc[i][j][rr]);
                }
        }
        __syncthreads();
        constexpr int ITERS = 128 * 16 / (WAVES * 64);
        if (vblk) {
            int b = row0 >> 10;
            int n0l = row0 & 1023;
            #pragma unroll
            for (int it = 0; it < ITERS; ++it) {
                int dl = it * (WAVES * 4) + (tid >> 4);
                int cc = tid & 15;
                h8 vv = *(const h8*)&E[dl * 136 + (cc << 3)];
                int hh = (col0 + dl - 512) >> 6, dd = (col0 + dl - 512) & 63;
                *(h8*)&vT[((size_t)((b << 3) + hh) * 64 + dd) * 1024 + n0l + (cc << 3)] = vv;
            }
        } else {
            #pragma unroll
            for (int it = 0; it < ITERS; ++it) {
                int rl = it * (WAVES * 4) + (tid >> 4);
                int cc = tid & 15;
                h8 vv = *(const h8*)&E[rl * 136 + (cc << 3)];
                *(h8*)&Cu[(size_t)(row0 + rl) * 2048 + col0 + (cc << 3)] = vv;
            }
        }
    } else {
        #pragma unroll
        for (int i = 0; i < WR; ++i) {
            #pragma unroll
            for (int j = 0; j < WC; ++j) {
                int colf = col0 + wc + (j << 4) + t;
                int rowb = row0 + wr + (i << 4) + (gq << 2);
                int b = rowb >> 10;
                #pragma unroll
                for (int rr = 0; rr < 4; ++rr) {
                    int row = rowb + rr;
                    float m = ((row & 1023) < slen[b]) ? 1.0f : 0.0f;
                    size_t ix = (size_t)row * 512 + colf;
                    Xio[ix] = (Xio[ix] + acc[i][j][rr] + bo[colf]) * m;
                }
            }
        }
    }
}

// ---------------------------------------------------------------- fused attention (MFMA, swapped QK^T)
// QBLK=128, 8 waves, K AND V double-buffered with full-iteration prefetch;
// counted vmcnt(2), raw barriers (no per-iteration drains).
__global__ __launch_bounds__(512) void k_attn(const _Float16* __restrict__ uvqk,
                                              const _Float16* __restrict__ vT,
                                              const float* __restrict__ posw,
                                              float* __restrict__ av0,
                                              float* __restrict__ av1,
                                              float* __restrict__ av2) {
    __shared__ _Float16 Ks[2][64 * 64];   // 16 KB
    __shared__ _Float16 Vs[2][64 * 64];   // 16 KB
    __shared__ _Float16 Ps[128 * 72];     // 18.4 KB (doubles as Q staging)
    __shared__ float pws[2][192];         // 1.5 KB   => 52.4 KB total, 3 blocks/CU
    int tid = threadIdx.x;
    int w = tid >> 6, lane = tid & 63;
    int t = lane & 15, gq = lane >> 4;
    int flat = blockIdx.x + 15 * (blockIdx.y + 8 * blockIdx.z);
    int f2 = (flat & 7) * 60 + (flat >> 3);
    int u = f2 % 15, h = (f2 / 15) & 7, b = f2 / 120;

    int qt, mlo, mhi;
    float* avout;
    if (u < 3) { qt = u; mlo = 0; mhi = 2 * qt + 1; avout = av0; }
    else if (u < 9) {
        int p = u - 3; qt = 3 + (p >> 1);
        int c0 = qt + 1;
        if (p & 1) { mlo = c0; mhi = 2 * qt + 1; avout = av1; }
        else       { mlo = 0;  mhi = c0 - 1; avout = av0; }
    } else {
        int p = u - 9; int third = p / 3; qt = 6 + third; int q3 = p - 3 * third;
        int c = 2 * qt + 2, c1 = (c + 2) / 3, c2 = (2 * c + 2) / 3;
        if (q3 == 0)      { mlo = 0;  mhi = c1 - 1; avout = av0; }
        else if (q3 == 1) { mlo = c1; mhi = c2 - 1; avout = av1; }
        else              { mlo = c2; mhi = 2 * qt + 1; avout = av2; }
    }
    int n0 = qt << 7;

    const _Float16* qbase = uvqk + (size_t)b * NN * 2048 + 1024 + h * 64;
    const _Float16* kbase = uvqk + (size_t)b * NN * 2048 + 1536 + h * 64;
    const _Float16* vbase = vT + (size_t)((b << 3) + h) * 64 * 1024;

    // prologue: Q(128 rows) -> Ps region, K(mlo) -> Ks[0], V(mlo) -> Vs[0], pws[0]
    #pragma unroll
    for (int q = 0; q < 2; ++q) {
        int s = (((w << 1) + q) << 6) + lane;
        int r = s >> 3, cs = (s & 7) ^ (r & 7);
        gl16(qbase + (size_t)(n0 + r) * 2048 + (cs << 3),
             (char*)Ps + (((w << 1) + q) << 10));
    }
    {
        int s = (w << 6) + lane;
        int r = s >> 3, cs = (s & 7) ^ (r & 7);
        gl16(kbase + (size_t)((mlo << 6) + r) * 2048 + (cs << 3),
             (char*)&Ks[0][0] + (w << 10));
        gl16(vbase + (size_t)r * 1024 + (mlo << 6) + (cs << 3),
             (char*)&Vs[0][0] + (w << 10));
    }
    if (tid < 192) pws[0][tid] = posw[(mlo << 6) - n0 + tid + 896];
    __syncthreads();

    h8 aq[2];
    {
        int rl = (w << 4) + t;
        #pragma unroll
        for (int ks = 0; ks < 2; ++ks)
            aq[ks] = *(const h8*)((const char*)Ps + rl * 128 +
                                  (((gq + (ks << 2)) ^ (rl & 7)) << 4));
    }
    asm volatile("s_waitcnt lgkmcnt(0)" ::: "memory");
    __builtin_amdgcn_sched_barrier(0);
    __syncthreads();   // all waves hold aq before Ps reused as P-matrix

    f4 zero4 = {0.0f, 0.0f, 0.0f, 0.0f};
    f4 avacc[4];
    #pragma unroll
    for (int j = 0; j < 4; ++j) avacc[j] = zero4;

    int cur = 0;
    for (int mt = mlo; mt <= mhi; ++mt) {
        int m0 = mt << 6;
        int mt2 = (mt < mhi) ? mt + 1 : mt;   // clamped: uniform vmcnt
        // issue next-tile K and V into the other buffers (stay in flight)
        {
            int s = (w << 6) + lane;
            int r = s >> 3, cs = (s & 7) ^ (r & 7);
            gl16(kbase + (size_t)((mt2 << 6) + r) * 2048 + (cs << 3),
                 (char*)&Ks[cur ^ 1][0] + (w << 10));
            gl16(vbase + (size_t)r * 1024 + (mt2 << 6) + (cs << 3),
                 (char*)&Vs[cur ^ 1][0] + (w << 10));
        }
        if (tid < 192) pws[cur ^ 1][tid] = posw[(mt2 << 6) - n0 + tid + 896];
        asm volatile("s_waitcnt vmcnt(2)" ::: "memory");   // K(mt),V(mt) landed; 2 newest in flight
        __builtin_amdgcn_s_barrier();                      // visible to all waves

        // S^T = K Q^T with rel-pos bias folded into MFMA C-in
        f4 sacc[4];
        __builtin_amdgcn_s_setprio(1);
        #pragma unroll
        for (int i = 0; i < 4; ++i) {
            f4 binit;
            #pragma unroll
            for (int rr = 0; rr < 4; ++rr)
                binit[rr] = pws[cur][127 + (i << 4) + (gq << 2) + rr - ((w << 4) + t)];
            int ml = (i << 4) + t;
            h8 ak0 = *(const h8*)((const char*)&Ks[cur][0] + ml * 128 + (((gq + 0) ^ (ml & 7)) << 4));
            h8 ak1 = *(const h8*)((const char*)&Ks[cur][0] + ml * 128 + (((gq + 4) ^ (ml & 7)) << 4));
            sacc[i] = __builtin_amdgcn_mfma_f32_16x16x32_f16(ak0, aq[0], binit, 0, 0, 0);
            sacc[i] = __builtin_amdgcn_mfma_f32_16x16x32_f16(ak1, aq[1], sacc[i], 0, 0, 0);
        }
        __builtin_amdgcn_s_setprio(0);
        // P = silu(S)*causal, packed h4 -> own-wave Ps rows
        int nabs = n0 + (w << 4) + t;
        #pragma unroll
        for (int i = 0; i < 4; ++i) {
            int mb = m0 + (i << 4) + (gq << 2);
            h4 pk;
            #pragma unroll
            for (int rr = 0; rr < 4; ++rr) {
                float p = (mb + rr <= nabs) ? fast_silu(sacc[i][rr]) : 0.0f;
                pk[rr] = (_Float16)p;
            }
            *(h4*)((char*)Ps + ((w << 4) + t) * 144 + (i << 5) + (gq << 3)) = pk;
        }
        asm volatile("s_waitcnt lgkmcnt(0)" ::: "memory");  // own Ps rows visible (self-read only)
        // AV += P @ V  (V[cur] landed + visible via top barrier)
        __builtin_amdgcn_s_setprio(1);
        #pragma unroll
        for (int ks = 0; ks < 2; ++ks) {
            h8 pa = *(const h8*)((const char*)Ps + ((w << 4) + t) * 144 + (ks << 6) + (gq << 4));
            #pragma unroll
            for (int jt = 0; jt < 4; ++jt) {
                int dl = (jt << 4) + t;
                h8 bv = *(const h8*)((const char*)&Vs[cur][0] + dl * 128 +
                                     (((gq + (ks << 2)) ^ (dl & 7)) << 4));
                avacc[jt] = __builtin_amdgcn_mfma_f32_16x16x32_f16(pa, bv, avacc[jt], 0, 0, 0);
            }
        }
        __builtin_amdgcn_s_setprio(0);
        __builtin_amdgcn_s_barrier();   // raw: reads of Ks/Vs[cur] done before next overwrite
        cur ^= 1;
    }
    asm volatile("s_waitcnt vmcnt(0)" ::: "memory");   // drain clamped tail prefetch

    #pragma unroll
    for (int jt = 0; jt < 4; ++jt) {
        #pragma unroll
        for (int rr = 0; rr < 4; ++rr) {
            int n = n0 + (w << 4) + (gq << 2) + rr;
            int d = (jt << 4) + t;
            avout[(size_t)(b * NN + n) * 512 + h * 64 + d] = avacc[jt][rr] * (1.0f / 1024.0f);
        }
    }
}

// ---------------------------------------------------------------- launch
extern "C" void kernel_launch(void* const* d_in, const int* in_sizes, int n_in,
                              void* d_out, int out_size, void* d_ws, size_t ws_size,
                              hipStream_t stream) {
    const float* seq   = (const float*)d_in[0];
    const int*   slen  = (const int*)d_in[1];
    const float* pos   = (const float*)d_in[2];
    const float* ln1g  = (const float*)d_in[3];
    const float* ln1b  = (const float*)d_in[4];
    const float* wuvqk = (const float*)d_in[5];
    const float* ln2g  = (const float*)d_in[6];
    const float* ln2b  = (const float*)d_in[7];
    const float* wo    = (const float*)d_in[8];
    const float* bo    = (const float*)d_in[9];
    const float* posw  = (const float*)d_in[10];

    float* x = (float*)d_out;
    char* W = (char*)d_ws;
    _Float16* nx16   = (_Float16*)(W);                       // 4 MiB
    _Float16* oin16  = (_Float16*)(W + (4u << 20));          // 4 MiB
    _Float16* uvqk16 = (_Float16*)(W + (8u << 20));          // 16 MiB
    _Float16* vT16   = (_Float16*)(W + (24u << 20));         // 4 MiB [b][h][d][n]
    float*    av0    = (float*)   (W + (28u << 20));         // 8 MiB
    float*    av1    = (float*)   (W + (36u << 20));         // 8 MiB
    float*    av2    = (float*)   (W + (44u << 20));         // 8 MiB
    _Float16* wuT16  = (_Float16*)(W + (52u << 20));         // 8 MiB [l][2048][512]
    _Float16* woT16  = (_Float16*)(W + (60u << 20));         // 2 MiB [l][512][512]

    k_prep<<<1792, 256, 0, stream>>>(wuvqk, wuT16, wo, woT16, seq, pos, slen,
                                     ln1g, ln1b, nx16, x);
    for (int l = 0; l < NBL; ++l) {
        if (l > 0)
            k_lnw<0><<<512, 256, 0, stream>>>(x, nullptr, nullptr,
                                              ln1g + l * 512, ln1b + l * 512, nx16, nullptr);
        k_gemm<0, 128, 128, 8, 2, 4><<<dim3(16, 32), 512, 0, stream>>>(
            nx16, wuT16 + (size_t)l * 2048 * 512, uvqk16, vT16, nullptr, nullptr, nullptr);
        k_attn<<<dim3(15, 8, NBL), 512, 0, stream>>>(uvqk16, vT16, posw + l * (2 * NN - 1),
                                                     av0, av1, av2);
        k_lnw<2><<<512, 256, 0, stream>>>(av0, av1, av2,
                                          ln2g + l * 512, ln2b + l * 512, oin16, uvqk16);
        k_gemm<1, 64, 64, 8, 2, 4><<<dim3(8, 64), 512, 0, stream>>>(
            oin16, woT16 + (size_t)l * 512 * 512, nullptr, nullptr, bo + l * 512, slen, x);
    }
    k_normw<<<512, 256, 0, stream>>>(x);
}

// Round 17
// 200.973 us; speedup vs baseline: 1.0085x; 1.0085x over previous
//
#include <hip/hip_runtime.h>
#include <math.h>
#include <stdint.h>

#define NN 1024
#define ROWS 4096
#define NBL 4

typedef _Float16 h8 __attribute__((ext_vector_type(8)));
typedef _Float16 h4 __attribute__((ext_vector_type(4)));
typedef float f4 __attribute__((ext_vector_type(4)));

__device__ __forceinline__ float fast_silu(float x) {
    float e = __builtin_amdgcn_exp2f(-1.4426950408889634f * x);
    return x * __builtin_amdgcn_rcpf(1.0f + e);
}

// async global->LDS, 16B/lane; LDS dest = wave-uniform base + lane*16
__device__ __forceinline__ void gl16(const void* gp, void* lp) {
    __builtin_amdgcn_global_load_lds(
        (const __attribute__((address_space(1))) uint32_t*)gp,
        (__attribute__((address_space(3))) uint32_t*)lp, 16, 0, 0);
}

__device__ __forceinline__ float wred(float s) {
    #pragma unroll
    for (int off = 1; off < 64; off <<= 1) s += __shfl_xor(s, off);
    return s;
}

// ---------------------------------------------------------------- prep: weight transposes + init+ln1(l=0)
// u<1024: wuT tile; u<1280: woT tile; u<1792: init 8 rows -> x (f32) and LN -> nx
__global__ __launch_bounds__(256) void k_prep(const float* __restrict__ wuvqk,
                                              _Float16* __restrict__ wuT,
                                              const float* __restrict__ wo,
                                              _Float16* __restrict__ woT,
                                              const float* __restrict__ seq,
                                              const float* __restrict__ pos,
                                              const int* __restrict__ slen,
                                              const float* __restrict__ g,
                                              const float* __restrict__ bt,
                                              _Float16* __restrict__ O,
                                              float* __restrict__ Xw) {
    __shared__ _Float16 T[64][66];
    int u = blockIdx.x, tid = threadIdx.x;
    if (u < 1280) {
        const float* s; _Float16* d; int N, n0, k0;
        if (u < 1024) {
            int z = u >> 8, t = u & 255;
            N = 2048; s = wuvqk + (size_t)z * 512 * 2048; d = wuT + (size_t)z * 2048 * 512;
            n0 = (t & 31) << 6; k0 = (t >> 5) << 6;
        } else {
            int v = u - 1024; int z = v >> 6, t = v & 63;
            N = 512; s = wo + (size_t)z * 512 * 512; d = woT + (size_t)z * 512 * 512;
            n0 = (t & 7) << 6; k0 = (t >> 3) << 6;
        }
        int tx = tid & 63, ty = tid >> 6;
        #pragma unroll
        for (int q = 0; q < 16; ++q)
            T[(q << 2) + ty][tx] = (_Float16)s[(size_t)(k0 + (q << 2) + ty) * N + n0 + tx];
        __syncthreads();
        #pragma unroll
        for (int q = 0; q < 16; ++q)
            d[(size_t)(n0 + (q << 2) + ty) * 512 + k0 + tx] = T[tx][(q << 2) + ty];
    } else {
        int vb = u - 1280;
        int w = tid >> 6, lane = tid & 63;
        int c = lane << 3;
        #pragma unroll
        for (int rr = 0; rr < 2; ++rr) {
            int row = (vb << 3) + (w << 1) + rr;
            int b = row >> 10, n = row & (NN - 1);
            float m = (n < slen[b]) ? 1.0f : 0.0f;
            const float4* sp = (const float4*)&seq[(size_t)row * 512 + c];
            const float4* pp = (const float4*)&pos[(size_t)n * 512 + c];
            const float SD = 22.627416997969522f;
            float4 s0 = sp[0], s1 = sp[1], p0 = pp[0], p1 = pp[1];
            float v[8];
            v[0]=(s0.x*SD+p0.x)*m; v[1]=(s0.y*SD+p0.y)*m; v[2]=(s0.z*SD+p0.z)*m; v[3]=(s0.w*SD+p0.w)*m;
            v[4]=(s1.x*SD+p1.x)*m; v[5]=(s1.y*SD+p1.y)*m; v[6]=(s1.z*SD+p1.z)*m; v[7]=(s1.w*SD+p1.w)*m;
            float4 o0, o1;
            o0.x=v[0]; o0.y=v[1]; o0.z=v[2]; o0.w=v[3];
            o1.x=v[4]; o1.y=v[5]; o1.z=v[6]; o1.w=v[7];
            float4* xp = (float4*)&Xw[(size_t)row * 512 + c];
            xp[0] = o0; xp[1] = o1;

            float s = v[0]+v[1]+v[2]+v[3]+v[4]+v[5]+v[6]+v[7];
            s = wred(s);
            float mu = s * (1.0f / 512.0f);
            float ss = 0.0f;
            #pragma unroll
            for (int i = 0; i < 8; ++i) { float d = v[i] - mu; ss += d * d; }
            ss = wred(ss);
            float rs = rsqrtf(ss * (1.0f / 512.0f) + 1e-6f);

            const float4* gp = (const float4*)&g[c];
            const float4* bp = (const float4*)&bt[c];
            float4 g0 = gp[0], g1 = gp[1], b0 = bp[0], b1 = bp[1];
            float gg[8] = {g0.x,g0.y,g0.z,g0.w,g1.x,g1.y,g1.z,g1.w};
            float bb[8] = {b0.x,b0.y,b0.z,b0.w,b1.x,b1.y,b1.z,b1.w};
            h8 oh;
            #pragma unroll
            for (int i = 0; i < 8; ++i) oh[i] = (_Float16)((v[i] - mu) * rs * gg[i] + bb[i]);
            *(h8*)&O[(size_t)row * 512 + c] = oh;
        }
    }
}

// ---------------------------------------------------------------- wave-level layernorm -> fp16
// MODE 0: x -> O ; MODE 2: av0(+av1 n>=384)(+av2 n>=768), LN, *U -> O
template<int MODE>
__global__ __launch_bounds__(256) void k_lnw(const float* __restrict__ X,
                                             const float* __restrict__ X2,
                                             const float* __restrict__ X3,
                                             const float* __restrict__ g,
                                             const float* __restrict__ bt,
                                             _Float16* __restrict__ O,
                                             const _Float16* __restrict__ U) {
    int tid = threadIdx.x;
    int w = tid >> 6, lane = tid & 63;
    int c = lane << 3;
    #pragma unroll
    for (int rr = 0; rr < 2; ++rr) {
        int row = (blockIdx.x << 3) + (w << 1) + rr;
        const float4* xp = (const float4*)&X[(size_t)row * 512 + c];
        float4 a = xp[0], b4 = xp[1];
        float v[8] = {a.x, a.y, a.z, a.w, b4.x, b4.y, b4.z, b4.w};
        if (MODE == 2) {
            int nn = row & (NN - 1);
            if (nn >= 384) {
                const float4* qp = (const float4*)&X2[(size_t)row * 512 + c];
                float4 t0 = qp[0], t1 = qp[1];
                v[0]+=t0.x; v[1]+=t0.y; v[2]+=t0.z; v[3]+=t0.w;
                v[4]+=t1.x; v[5]+=t1.y; v[6]+=t1.z; v[7]+=t1.w;
            }
            if (nn >= 768) {
                const float4* qp = (const float4*)&X3[(size_t)row * 512 + c];
                float4 t0 = qp[0], t1 = qp[1];
                v[0]+=t0.x; v[1]+=t0.y; v[2]+=t0.z; v[3]+=t0.w;
                v[4]+=t1.x; v[5]+=t1.y; v[6]+=t1.z; v[7]+=t1.w;
            }
        }
        float s = v[0]+v[1]+v[2]+v[3]+v[4]+v[5]+v[6]+v[7];
        s = wred(s);
        float mu = s * (1.0f / 512.0f);
        float ss = 0.0f;
        #pragma unroll
        for (int i = 0; i < 8; ++i) { float d = v[i] - mu; ss += d * d; }
        ss = wred(ss);
        float rs = rsqrtf(ss * (1.0f / 512.0f) + 1e-6f);

        const float4* gp = (const float4*)&g[c];
        const float4* bp = (const float4*)&bt[c];
        float4 g0 = gp[0], g1 = gp[1], b0 = bp[0], b1 = bp[1];
        float gg[8] = {g0.x,g0.y,g0.z,g0.w,g1.x,g1.y,g1.z,g1.w};
        float bb[8] = {b0.x,b0.y,b0.z,b0.w,b1.x,b1.y,b1.z,b1.w};
        float o[8];
        #pragma unroll
        for (int i = 0; i < 8; ++i) o[i] = (v[i] - mu) * rs * gg[i] + bb[i];
        if (MODE == 2) {
            h8 uu = *(const h8*)&U[(size_t)row * 2048 + c];
            #pragma unroll
            for (int i = 0; i < 8; ++i) o[i] *= (float)uu[i];
        }
        h8 oh;
        #pragma unroll
        for (int i = 0; i < 8; ++i) oh[i] = (_Float16)o[i];
        *(h8*)&O[(size_t)row * 512 + c] = oh;
    }
}

// ---------------------------------------------------------------- final L2 norm (wave/row)
__global__ __launch_bounds__(256) void k_normw(float* __restrict__ X) {
    int tid = threadIdx.x;
    int w = tid >> 6, lane = tid & 63;
    int c = lane << 3;
    #pragma unroll
    for (int rr = 0; rr < 2; ++rr) {
        int row = (blockIdx.x << 3) + (w << 1) + rr;
        float4* xp = (float4*)&X[(size_t)row * 512 + c];
        float4 a = xp[0], b4 = xp[1];
        float ss = a.x*a.x + a.y*a.y + a.z*a.z + a.w*a.w +
                   b4.x*b4.x + b4.y*b4.y + b4.z*b4.z + b4.w*b4.w;
        ss = wred(ss);
        float sc = 1.0f / fmaxf(sqrtf(ss), 1e-6f);
        a.x*=sc; a.y*=sc; a.z*=sc; a.w*=sc; b4.x*=sc; b4.y*=sc; b4.z*=sc; b4.w*=sc;
        xp[0] = a; xp[1] = b4;
    }
}

// ---------------------------------------------------------------- MFMA GEMM (fp16 in, f32 acc)
// EPI 0 (uvqk): LDS-staged epilogue, coalesced h8 stores; v-blocks transposed -> vT
// EPI 1: X = (X + C + bo) * mask
template<int EPI, int BM, int BN, int WAVES, int WGR, int WGC>
__global__ __launch_bounds__(WAVES * 64) void k_gemm(const _Float16* __restrict__ A,
                                                     const _Float16* __restrict__ Bm,
                                                     _Float16* __restrict__ Cu,
                                                     _Float16* __restrict__ vT,
                                                     const float* __restrict__ bo,
                                                     const int* __restrict__ slen,
                                                     float* __restrict__ Xio) {
    constexpr int WR = BM / WGR / 16;
    constexpr int WC = BN / WGC / 16;
    constexpr int QA = BM * 8 / (WAVES * 64);
    constexpr int QB = BN * 8 / (WAVES * 64);
    __shared__ _Float16 smem[2 * 64 * (BM + BN)];
    _Float16* AsB = smem;                    // [2][BM*64]
    _Float16* BsB = smem + 2 * BM * 64;      // [2][BN*64]
    int tid = threadIdx.x;
    int w = tid >> 6, lane = tid & 63;
    int t = lane & 15, gq = lane >> 4;
    int flat = blockIdx.y * gridDim.x + blockIdx.x;
    int cpx = (gridDim.x * gridDim.y) >> 3;
    int f2 = (flat & 7) * cpx + (flat >> 3);
    int bx = f2 % gridDim.x, by = f2 / gridDim.x;
    int row0 = by * BM, col0 = bx * BN;
    int wr = (w / WGC) * (BM / WGR), wc = (w % WGC) * (BN / WGC);

    f4 zero4 = {0.0f, 0.0f, 0.0f, 0.0f};
    f4 acc[WR][WC];
    #pragma unroll
    for (int i = 0; i < WR; ++i)
        #pragma unroll
        for (int j = 0; j < WC; ++j) acc[i][j] = zero4;

    auto stage = [&](int buf, int k0) {
        _Float16* As = AsB + buf * BM * 64;
        _Float16* Bs = BsB + buf * BN * 64;
        #pragma unroll
        for (int q = 0; q < QA; ++q) {
            int s = (q * WAVES + w) * 64 + lane;
            int r = s >> 3, cs = (s & 7) ^ (r & 7);
            gl16(A + (size_t)(row0 + r) * 512 + k0 + (cs << 3),
                 (char*)As + (size_t)(q * WAVES + w) * 1024);
        }
        #pragma unroll
        for (int q = 0; q < QB; ++q) {
            int s = (q * WAVES + w) * 64 + lane;
            int r = s >> 3, cs = (s & 7) ^ (r & 7);
            gl16(Bm + (size_t)(col0 + r) * 512 + k0 + (cs << 3),
                 (char*)Bs + (size_t)(q * WAVES + w) * 1024);
        }
    };

    stage(0, 0);
    int cur = 0;
    for (int k0 = 0; k0 < 512; k0 += 64) {
        __syncthreads();
        if (k0 + 64 < 512) stage(cur ^ 1, k0 + 64);
        const char* As = (const char*)(AsB + cur * BM * 64);
        const char* Bs = (const char*)(BsB + cur * BN * 64);
        h8 af[WR][2], bf[WC][2];
        #pragma unroll
        for (int i = 0; i < WR; ++i) {
            int rl = wr + (i << 4) + t;
            #pragma unroll
            for (int ks = 0; ks < 2; ++ks)
                af[i][ks] = *(const h8*)(As + rl * 128 + (((gq + (ks << 2)) ^ (rl & 7)) << 4));
        }
        #pragma unroll
        for (int j = 0; j < WC; ++j) {
            int nl = wc + (j << 4) + t;
            #pragma unroll
            for (int ks = 0; ks < 2; ++ks)
                bf[j][ks] = *(const h8*)(Bs + nl * 128 + (((gq + (ks << 2)) ^ (nl & 7)) << 4));
        }
        #pragma unroll
        for (int i = 0; i < WR; ++i)
            #pragma unroll
            for (int j = 0; j < WC; ++j) {
                acc[i][j] = __builtin_amdgcn_mfma_f32_16x16x32_f16(af[i][0], bf[j][0], acc[i][j], 0, 0, 0);
                acc[i][j] = __builtin_amdgcn_mfma_f32_16x16x32_f16(af[i][1], bf[j][1], acc[i][j], 0, 0, 0);
            }
        cur ^= 1;
    }

    if (EPI == 0) {
        // LDS-staged epilogue: E stride 136 h2; v-blocks stored transposed
        _Float16* E = smem;   // 128*136 h2 = 34816 B
        bool vblk = (col0 >= 512 && col0 < 1024);
        __syncthreads();   // all MFMA LDS reads done
        if (vblk) {
            #pragma unroll
            for (int i = 0; i < WR; ++i)
                #pragma unroll
                for (int j = 0; j < WC; ++j) {
                    int cl = wc + (j << 4) + t;
                    int rl = wr + (i << 4) + (gq << 2);
                    h4 pk;
                    #pragma unroll
                    for (int rr = 0; rr < 4; ++rr) pk[rr] = (_Float16)fast_silu(acc[i][j][rr]);
                    *(h4*)&E[cl * 136 + rl] = pk;   // E_T[d][n]
                }
        } else {
            #pragma unroll
            for (int i = 0; i < WR; ++i)
                #pragma unroll
                for (int j = 0; j < WC; ++j) {
                    int cl = wc + (j << 4) + t;
                    int rl = wr + (i << 4) + (gq << 2);
                    #pragma unroll
                    for (int rr = 0; rr < 4; ++rr)
                        E[(rl + rr) * 136 + cl] = (_Float16)fast_silu(acc[i][j][rr]);
                }
        }
        __syncthreads();
        constexpr int ITERS = 128 * 16 / (WAVES * 64);
        if (vblk) {
            int b = row0 >> 10;
            int n0l = row0 & 1023;
            #pragma unroll
            for (int it = 0; it < ITERS; ++it) {
                int dl = it * (WAVES * 4) + (tid >> 4);
                int cc = tid & 15;
                h8 vv = *(const h8*)&E[dl * 136 + (cc << 3)];
                int hh = (col0 + dl - 512) >> 6, dd = (col0 + dl - 512) & 63;
                *(h8*)&vT[((size_t)((b << 3) + hh) * 64 + dd) * 1024 + n0l + (cc << 3)] = vv;
            }
        } else {
            #pragma unroll
            for (int it = 0; it < ITERS; ++it) {
                int rl = it * (WAVES * 4) + (tid >> 4);
                int cc = tid & 15;
                h8 vv = *(const h8*)&E[rl * 136 + (cc << 3)];
                *(h8*)&Cu[(size_t)(row0 + rl) * 2048 + col0 + (cc << 3)] = vv;
            }
        }
    } else {
        #pragma unroll
        for (int i = 0; i < WR; ++i) {
            #pragma unroll
            for (int j = 0; j < WC; ++j) {
                int colf = col0 + wc + (j << 4) + t;
                int rowb = row0 + wr + (i << 4) + (gq << 2);
                int b = rowb >> 10;
                #pragma unroll
                for (int rr = 0; rr < 4; ++rr) {
                    int row = rowb + rr;
                    float m = ((row & 1023) < slen[b]) ? 1.0f : 0.0f;
                    size_t ix = (size_t)row * 512 + colf;
                    Xio[ix] = (Xio[ix] + acc[i][j][rr] + bo[colf]) * m;
                }
            }
        }
    }
}

// ---------------------------------------------------------------- fused attention (MFMA, swapped QK^T)
// QBLK=128, 8 waves. 15 units per (b,h).
__global__ __launch_bounds__(512) void k_attn(const _Float16* __restrict__ uvqk,
                                              const _Float16* __restrict__ vT,
                                              const float* __restrict__ posw,
                                              float* __restrict__ av0,
                                              float* __restrict__ av1,
                                              float* __restrict__ av2) {
    __shared__ _Float16 Ks[2][64 * 64];   // 16 KB
    __shared__ _Float16 Vs[64 * 64];      // 8 KB, single-buffered
    __shared__ _Float16 Ps[128 * 72];     // 18.4 KB (doubles as Q staging)
    __shared__ float pws[2][192];
    int tid = threadIdx.x;
    int w = tid >> 6, lane = tid & 63;
    int t = lane & 15, gq = lane >> 4;
    int flat = blockIdx.x + 15 * (blockIdx.y + 8 * blockIdx.z);
    int f2 = (flat & 7) * 60 + (flat >> 3);
    int u = f2 % 15, h = (f2 / 15) & 7, b = f2 / 120;

    int qt, mlo, mhi;
    float* avout;
    if (u < 3) { qt = u; mlo = 0; mhi = 2 * qt + 1; avout = av0; }
    else if (u < 9) {
        int p = u - 3; qt = 3 + (p >> 1);
        int c0 = qt + 1;
        if (p & 1) { mlo = c0; mhi = 2 * qt + 1; avout = av1; }
        else       { mlo = 0;  mhi = c0 - 1; avout = av0; }
    } else {
        int p = u - 9; int third = p / 3; qt = 6 + third; int q3 = p - 3 * third;
        int c = 2 * qt + 2, c1 = (c + 2) / 3, c2 = (2 * c + 2) / 3;
        if (q3 == 0)      { mlo = 0;  mhi = c1 - 1; avout = av0; }
        else if (q3 == 1) { mlo = c1; mhi = c2 - 1; avout = av1; }
        else              { mlo = c2; mhi = 2 * qt + 1; avout = av2; }
    }
    int n0 = qt << 7;

    const _Float16* qbase = uvqk + (size_t)b * NN * 2048 + 1024 + h * 64;
    const _Float16* kbase = uvqk + (size_t)b * NN * 2048 + 1536 + h * 64;
    const _Float16* vbase = vT + (size_t)((b << 3) + h) * 64 * 1024;

    // prologue: Q(128 rows) -> Ps region, K(mlo) -> Ks[0], pws[0]
    #pragma unroll
    for (int q = 0; q < 2; ++q) {
        int s = (((w << 1) + q) << 6) + lane;
        int r = s >> 3, cs = (s & 7) ^ (r & 7);
        gl16(qbase + (size_t)(n0 + r) * 2048 + (cs << 3),
             (char*)Ps + (((w << 1) + q) << 10));
    }
    {
        int s = (w << 6) + lane;
        int r = s >> 3, cs = (s & 7) ^ (r & 7);
        gl16(kbase + (size_t)((mlo << 6) + r) * 2048 + (cs << 3),
             (char*)&Ks[0][0] + (w << 10));
    }
    if (tid < 192) pws[0][tid] = posw[(mlo << 6) - n0 + tid + 896];
    __syncthreads();

    h8 aq[2];
    {
        int rl = (w << 4) + t;
        #pragma unroll
        for (int ks = 0; ks < 2; ++ks)
            aq[ks] = *(const h8*)((const char*)Ps + rl * 128 +
                                  (((gq + (ks << 2)) ^ (rl & 7)) << 4));
    }
    asm volatile("s_waitcnt lgkmcnt(0)" ::: "memory");
    __builtin_amdgcn_sched_barrier(0);
    __syncthreads();   // all waves hold aq before Ps reused as P-matrix

    f4 zero4 = {0.0f, 0.0f, 0.0f, 0.0f};
    f4 avacc[4];
    #pragma unroll
    for (int j = 0; j < 4; ++j) avacc[j] = zero4;

    int cur = 0;
    for (int mt = mlo; mt <= mhi; ++mt) {
        int m0 = mt << 6;
        {
            int s = (w << 6) + lane;
            int r = s >> 3, cs = (s & 7) ^ (r & 7);
            gl16(vbase + (size_t)r * 1024 + m0 + (cs << 3),
                 (char*)&Vs[0] + (w << 10));
        }
        int mt2 = (mt < mhi) ? mt + 1 : mt;
        {
            int s = (w << 6) + lane;
            int r = s >> 3, cs = (s & 7) ^ (r & 7);
            gl16(kbase + (size_t)((mt2 << 6) + r) * 2048 + (cs << 3),
                 (char*)&Ks[cur ^ 1][0] + (w << 10));
        }
        if (tid < 192) pws[cur ^ 1][tid] = posw[(mt2 << 6) - n0 + tid + 896];

        f4 sacc[4];
        __builtin_amdgcn_s_setprio(1);
        #pragma unroll
        for (int i = 0; i < 4; ++i) {
            f4 binit;
            #pragma unroll
            for (int rr = 0; rr < 4; ++rr)
                binit[rr] = pws[cur][127 + (i << 4) + (gq << 2) + rr - ((w << 4) + t)];
            int ml = (i << 4) + t;
            h8 ak0 = *(const h8*)((const char*)&Ks[cur][0] + ml * 128 + (((gq + 0) ^ (ml & 7)) << 4));
            h8 ak1 = *(const h8*)((const char*)&Ks[cur][0] + ml * 128 + (((gq + 4) ^ (ml & 7)) << 4));
            sacc[i] = __builtin_amdgcn_mfma_f32_16x16x32_f16(ak0, aq[0], binit, 0, 0, 0);
            sacc[i] = __builtin_amdgcn_mfma_f32_16x16x32_f16(ak1, aq[1], sacc[i], 0, 0, 0);
        }
        __builtin_amdgcn_s_setprio(0);
        int nabs = n0 + (w << 4) + t;
        #pragma unroll
        for (int i = 0; i < 4; ++i) {
            int mb = m0 + (i << 4) + (gq << 2);
            h4 pk;
            #pragma unroll
            for (int rr = 0; rr < 4; ++rr) {
                float p = (mb + rr <= nabs) ? fast_silu(sacc[i][rr]) : 0.0f;
                pk[rr] = (_Float16)p;
            }
            *(h4*)((char*)Ps + ((w << 4) + t) * 144 + (i << 5) + (gq << 3)) = pk;
        }
        asm volatile("s_waitcnt lgkmcnt(0)" ::: "memory");
        asm volatile("s_waitcnt vmcnt(1)" ::: "memory");
        __builtin_amdgcn_s_barrier();
        __builtin_amdgcn_s_setprio(1);
        #pragma unroll
        for (int ks = 0; ks < 2; ++ks) {
            h8 pa = *(const h8*)((const char*)Ps + ((w << 4) + t) * 144 + (ks << 6) + (gq << 4));
            #pragma unroll
            for (int jt = 0; jt < 4; ++jt) {
                int dl = (jt << 4) + t;
                h8 bv = *(const h8*)((const char*)&Vs[0] + dl * 128 +
                                     (((gq + (ks << 2)) ^ (dl & 7)) << 4));
                avacc[jt] = __builtin_amdgcn_mfma_f32_16x16x32_f16(pa, bv, avacc[jt], 0, 0, 0);
            }
        }
        __builtin_amdgcn_s_setprio(0);
        __syncthreads();
        cur ^= 1;
    }

    #pragma unroll
    for (int jt = 0; jt < 4; ++jt) {
        #pragma unroll
        for (int rr = 0; rr < 4; ++rr) {
            int n = n0 + (w << 4) + (gq << 2) + rr;
            int d = (jt << 4) + t;
            avout[(size_t)(b * NN + n) * 512 + h * 64 + d] = avacc[jt][rr] * (1.0f / 1024.0f);
        }
    }
}

// ---------------------------------------------------------------- launch
extern "C" void kernel_launch(void* const* d_in, const int* in_sizes, int n_in,
                              void* d_out, int out_size, void* d_ws, size_t ws_size,
                              hipStream_t stream) {
    const float* seq   = (const float*)d_in[0];
    const int*   slen  = (const int*)d_in[1];
    const float* pos   = (const float*)d_in[2];
    const float* ln1g  = (const float*)d_in[3];
    const float* ln1b  = (const float*)d_in[4];
    const float* wuvqk = (const float*)d_in[5];
    const float* ln2g  = (const float*)d_in[6];
    const float* ln2b  = (const float*)d_in[7];
    const float* wo    = (const float*)d_in[8];
    const float* bo    = (const float*)d_in[9];
    const float* posw  = (const float*)d_in[10];

    float* x = (float*)d_out;
    char* W = (char*)d_ws;
    _Float16* nx16   = (_Float16*)(W);                       // 4 MiB
    _Float16* oin16  = (_Float16*)(W + (4u << 20));          // 4 MiB
    _Float16* uvqk16 = (_Float16*)(W + (8u << 20));          // 16 MiB
    _Float16* vT16   = (_Float16*)(W + (24u << 20));         // 4 MiB [b][h][d][n]
    float*    av0    = (float*)   (W + (28u << 20));         // 8 MiB
    float*    av1    = (float*)   (W + (36u << 20));         // 8 MiB
    float*    av2    = (float*)   (W + (44u << 20));         // 8 MiB
    _Float16* wuT16  = (_Float16*)(W + (52u << 20));         // 8 MiB [l][2048][512]
    _Float16* woT16  = (_Float16*)(W + (60u << 20));         // 2 MiB [l][512][512]

    k_prep<<<1792, 256, 0, stream>>>(wuvqk, wuT16, wo, woT16, seq, pos, slen,
                                     ln1g, ln1b, nx16, x);
    for (int l = 0; l < NBL; ++l) {
        if (l > 0)
            k_lnw<0><<<512, 256, 0, stream>>>(x, nullptr, nullptr,
                                              ln1g + l * 512, ln1b + l * 512, nx16, nullptr);
        k_gemm<0, 128, 128, 8, 2, 4><<<dim3(16, 32), 512, 0, stream>>>(
            nx16, wuT16 + (size_t)l * 2048 * 512, uvqk16, vT16, nullptr, nullptr, nullptr);
        k_attn<<<dim3(15, 8, NBL), 512, 0, stream>>>(uvqk16, vT16, posw + l * (2 * NN - 1),
                                                     av0, av1, av2);
        k_lnw<2><<<512, 256, 0, stream>>>(av0, av1, av2,
                                          ln2g + l * 512, ln2b + l * 512, oin16, uvqk16);
        k_gemm<1, 64, 64, 8, 2, 4><<<dim3(8, 64), 512, 0, stream>>>(
            oin16, woT16 + (size_t)l * 512 * 512, nullptr, nullptr, bo + l * 512, slen, x);
    }
    k_normw<<<512, 256, 0, stream>>>(x);
}